// Round 11
// baseline (79.379 us; speedup 1.0000x reference)
//
#include <hip/hip_runtime.h>
#include <hip/hip_bf16.h>

#define NUM_GT 25
#define NUM_PRED 40
#define NBLOCKS 1536         // 6 blocks/CU x 256 CUs
#define BLOCK 320            // 5 waves
#define ROWS 128

// ws layout (u32 words):
//   [r*65 + s], r=0..127 : partial SAD sums; sbin s: 0..24 = g_gt(s),
//                          25..64 = g_pr(s-25)
//   [WS_OV + p], p=0..40 : overlap bitmask row p
#define WS_OV    (ROWS * 65)
#define WS_WORDS (WS_OV + 41)

#define SAD(A, W, K) asm("v_sad_u8 %0, %1, %2, %0" : "+v"(A) : "v"(W), "s"(K))

__device__ __forceinline__ unsigned pack_i4(int4 v) {
    return (unsigned)v.x | ((unsigned)v.y << 8) |
           ((unsigned)v.z << 16) | ((unsigned)v.w << 24);
}
__device__ __forceinline__ unsigned pack_f4(float4 v) {
    return (unsigned)v.x | ((unsigned)v.y << 8) |
           ((unsigned)v.z << 16) | ((unsigned)v.w << 24);
}

template <int NB>
__device__ __forceinline__ void reduce_flush(
    unsigned* acc, int sbin0, int lane, unsigned* __restrict__ ws, int row)
{
    #pragma unroll
    for (int j = 0; j < NB; ++j) {
        unsigned c = acc[j];
        c += __shfl_down(c, 32, 64);
        c += __shfl_down(c, 16, 64);
        c += __shfl_down(c, 8, 64);
        c += __shfl_down(c, 4, 64);
        c += __shfl_down(c, 2, 64);
        c += __shfl_down(c, 1, 64);
        if (lane == 0 && c) atomicAdd(&ws[row * 65 + sbin0 + j], c);
    }
}

// single-array gt wave: 16 vox/lane/iter (4 x dwordx4 in flight)
template <int NB>
__device__ __forceinline__ void scan_gt16(
    const int4* __restrict__ g4, int kb0, int nch, int lane,
    unsigned* __restrict__ ws, int row)
{
    unsigned acc[NB];
    #pragma unroll
    for (int j = 0; j < NB; ++j) acc[j] = 0u;

    for (int c = blockIdx.x; c < nch; c += NBLOCKS) {
        const int q = c * 256 + lane * 4;
        int4 w0 = g4[q], w1 = g4[q + 1], w2 = g4[q + 2], w3 = g4[q + 3];
        unsigned A = pack_i4(w0), B = pack_i4(w1), C = pack_i4(w2), D = pack_i4(w3);
        #pragma unroll
        for (int j = 0; j < NB; ++j) {
            const unsigned K = (unsigned)((kb0 + j) * 0x01010101u);
            SAD(acc[j], A, K); SAD(acc[j], B, K);
            SAD(acc[j], C, K); SAD(acc[j], D, K);
        }
    }
    reduce_flush<NB>(acc, kb0, lane, ws, row);
}

// single-array pred wave: 16 vox/lane/iter
template <int NB>
__device__ __forceinline__ void scan_pr16(
    const float4* __restrict__ p4, int kb0, int nch, int lane,
    unsigned* __restrict__ ws, int row)
{
    unsigned acc[NB];
    #pragma unroll
    for (int j = 0; j < NB; ++j) acc[j] = 0u;

    for (int c = blockIdx.x; c < nch; c += NBLOCKS) {
        const int q = c * 256 + lane * 4;
        float4 w0 = p4[q], w1 = p4[q + 1], w2 = p4[q + 2], w3 = p4[q + 3];
        unsigned A = pack_f4(w0), B = pack_f4(w1), C = pack_f4(w2), D = pack_f4(w3);
        #pragma unroll
        for (int j = 0; j < NB; ++j) {
            const unsigned K = (unsigned)((kb0 + j) * 0x01010101u);
            SAD(acc[j], A, K); SAD(acc[j], B, K);
            SAD(acc[j], C, K); SAD(acc[j], D, K);
        }
    }
    reduce_flush<NB>(acc, 25 + kb0, lane, ws, row);
}

// wave 0: gt g(0..12) + overlap matrix; 8 vox/lane/iter, both arrays (4 loads)
__device__ __forceinline__ void scan_mixed8(
    const float4* __restrict__ p4, const int4* __restrict__ g4,
    int nch, int lane, unsigned* __restrict__ ws, int row, unsigned* sovl)
{
    // wave-local init; only wave 0 touches sovl -> no block barrier needed
    sovl[lane] = 0u;

    unsigned acc[13];
    #pragma unroll
    for (int j = 0; j < 13; ++j) acc[j] = 0u;

    for (int c = blockIdx.x; c < nch; c += NBLOCKS) {
        const int q = c * 128 + lane * 2;
        int4  ga = g4[q], gb = g4[q + 1];
        float4 pa = p4[q], pb = p4[q + 1];

        unsigned a0 = (unsigned)ga.x, a1 = (unsigned)ga.y;
        unsigned a2 = (unsigned)ga.z, a3 = (unsigned)ga.w;
        unsigned a4 = (unsigned)gb.x, a5 = (unsigned)gb.y;
        unsigned a6 = (unsigned)gb.z, a7 = (unsigned)gb.w;
        unsigned b0 = (unsigned)pa.x, b1 = (unsigned)pa.y;
        unsigned b2 = (unsigned)pa.z, b3 = (unsigned)pa.w;
        unsigned b4 = (unsigned)pb.x, b5 = (unsigned)pb.y;
        unsigned b6 = (unsigned)pb.z, b7 = (unsigned)pb.w;

        unsigned ok = (sovl[b0 & 63] >> (a0 & 31)) & (sovl[b1 & 63] >> (a1 & 31))
                    & (sovl[b2 & 63] >> (a2 & 31)) & (sovl[b3 & 63] >> (a3 & 31))
                    & (sovl[b4 & 63] >> (a4 & 31)) & (sovl[b5 & 63] >> (a5 & 31))
                    & (sovl[b6 & 63] >> (a6 & 31)) & (sovl[b7 & 63] >> (a7 & 31));
        if (!(ok & 1u)) {                    // rare after warm-up
            atomicOr(&sovl[b0 & 63], 1u << (a0 & 31));
            atomicOr(&sovl[b1 & 63], 1u << (a1 & 31));
            atomicOr(&sovl[b2 & 63], 1u << (a2 & 31));
            atomicOr(&sovl[b3 & 63], 1u << (a3 & 31));
            atomicOr(&sovl[b4 & 63], 1u << (a4 & 31));
            atomicOr(&sovl[b5 & 63], 1u << (a5 & 31));
            atomicOr(&sovl[b6 & 63], 1u << (a6 & 31));
            atomicOr(&sovl[b7 & 63], 1u << (a7 & 31));
        }

        unsigned GA = a0 | (a1 << 8) | (a2 << 16) | (a3 << 24);
        unsigned GB = a4 | (a5 << 8) | (a6 << 16) | (a7 << 24);
        #pragma unroll
        for (int j = 0; j < 13; ++j) {
            const unsigned K = (unsigned)(j * 0x01010101u);
            SAD(acc[j], GA, K); SAD(acc[j], GB, K);
        }
    }
    reduce_flush<13>(acc, 0, lane, ws, row);

    if (lane < 41) {
        unsigned v = sovl[lane];
        if (v) atomicOr(&ws[WS_OV + lane], v);
    }
}

// ---------------------------------------------------------------------------
// Histogram: 5-wave blocks, bins split 13/12/14/13/13; each wave streams
// directly from global with 4 dwordx4 in flight (64 B/lane), <=14 clean-VGPR
// accumulators (R9 evidence: no AGPR round-trip tax), no barriers, grid
// 1536 = 6 blocks/CU -> 30/32 wave slots.
// ---------------------------------------------------------------------------
__global__ __launch_bounds__(BLOCK, 8) void hist_kernel(
    const float* __restrict__ pred, const int* __restrict__ gt,
    unsigned* __restrict__ ws, int n)
{
    __shared__ unsigned sovl[64];
    const int tid  = threadIdx.x;
    const int lane = tid & 63;
    const int wave = tid >> 6;

    const int nch16 = n / 1024;              // 1024-voxel chunks (waves 1-4)
    const int nch8  = n / 512;               // 512-voxel chunks (wave 0)
    const int row = blockIdx.x & (ROWS - 1);
    const float4* __restrict__ p4 = (const float4*)pred;
    const int4* __restrict__  g4 = (const int4*)gt;

    if      (wave == 0) scan_mixed8(p4, g4, nch8, lane, ws, row, sovl);
    else if (wave == 1) scan_gt16<12>(g4, 13, nch16, lane, ws, row);
    else if (wave == 2) scan_pr16<14>(p4, 0, nch16, lane, ws, row);
    else if (wave == 3) scan_pr16<13>(p4, 14, nch16, lane, ws, row);
    else                scan_pr16<13>(p4, 27, nch16, lane, ws, row);

    // defensive tails (empty for n = 256^3)
    if (blockIdx.x == 0 && tid == 0) {
        for (int v = nch16 * 1024; v < n; ++v) {   // waves 1-4 coverage
            int p = (int)pred[v];
            int g = gt[v];
            for (int b = 13; b < 25; ++b) atomicAdd(&ws[b], (unsigned)abs(g - b));
            for (int b = 0; b < 40; ++b) atomicAdd(&ws[25 + b], (unsigned)abs(p - b));
        }
        for (int v = nch8 * 512; v < n; ++v) {     // wave 0 coverage
            int p = (int)pred[v];
            int g = gt[v];
            for (int b = 0; b < 13; ++b) atomicAdd(&ws[b], (unsigned)abs(g - b));
            atomicOr(&ws[WS_OV + min(max(p, 0), NUM_PRED)], 1u << (g & 31));
        }
    }
}

// ---------------------------------------------------------------------------
// Finisher: sum 128 partial rows, exact second-difference counts (int64) +
// fp64 dice (proven absmax = 0, rounds 6-10).
// ---------------------------------------------------------------------------
__global__ __launch_bounds__(128) void finish_kernel(
    const unsigned* __restrict__ ws, float* __restrict__ out, int n)
{
    __shared__ long long gsum[65];
    __shared__ long long psz[41];
    __shared__ unsigned ovs[41];
    const int t = threadIdx.x;

    if (t < 65) {
        unsigned s = 0;
        for (int r = 0; r < ROWS; ++r) s += ws[r * 65 + t];
        gsum[t] = (long long)s;
    }
    if (t < 41) ovs[t] = ws[WS_OV + t];
    __syncthreads();

    const long long N = n;
    if (t < 41) {                            // pred_sizes[P], P = t
        const long long Sp = gsum[25];
        int P = t;
        long long f;
        if (P == 0)       f = (N - gsum[25 + 0] + gsum[25 + 1]) / 2;
        else if (P <= 38) f = (gsum[25 + P - 1] - 2 * gsum[25 + P] + gsum[25 + P + 1]) / 2;
        else if (P == 39) f = (gsum[25 + 38] - 2 * gsum[25 + 39] + (40 * N - Sp)) / 2;
        else              f = (gsum[25 + 39] - 39 * N + Sp) / 2;   // P = 40
        psz[P] = f;
    }
    __syncthreads();

    if (t < 64) {
        const int lane = t;
        const long long Sg = gsum[0];
        double dice = 0.0;
        int present = 0;
        if (lane < 25) {                     // gt component label L = lane+1
            int L = lane + 1;
            long long gs;
            if (L <= 23)      gs = (gsum[L - 1] - 2 * gsum[L] + gsum[L + 1]) / 2;
            else if (L == 24) gs = (gsum[23] - 2 * gsum[24] + (25 * N - Sg)) / 2;
            else              gs = (gsum[24] - 24 * N + Sg) / 2;   // L = 25
            if (gs > 0) {
                present = 1;
                double un = 0.0;
                const unsigned bit = 1u << L;
                for (int p = 0; p < 41; ++p)
                    if (ovs[p] & bit) un += (double)psz[p];
                dice = 2.0 * (double)gs / (un + (double)gs + 1.0);
            }
        }
        int fp = 0;
        if (lane < 41) {
            if (psz[lane] > 0 && (ovs[lane] & 0x3FFFFFEu) == 0) fp = 1;
        }

        int num_gt = __popcll(__ballot(present != 0));
        int nfp    = __popcll(__ballot(fp != 0));
        #pragma unroll
        for (int o = 32; o >= 1; o >>= 1) dice += __shfl_xor(dice, o, 64);

        if (lane == 0) out[0] = (float)(dice / (double)(num_gt + nfp));
    }
}

extern "C" void kernel_launch(void* const* d_in, const int* in_sizes, int n_in,
                              void* d_out, int out_size, void* d_ws, size_t ws_size,
                              hipStream_t stream) {
    const float* pred = (const float*)d_in[0];
    const int* gt = (const int*)d_in[1];
    float* out = (float*)d_out;
    unsigned* ws = (unsigned*)d_ws;
    const int n = in_sizes[0];

    hipMemsetAsync(ws, 0, WS_WORDS * sizeof(unsigned), stream);

    hist_kernel<<<NBLOCKS, BLOCK, 0, stream>>>(pred, gt, ws, n);
    finish_kernel<<<1, 128, 0, stream>>>(ws, out, n);
}

// Round 12
// 45.981 us; speedup vs baseline: 1.7263x; 1.7263x over previous
//
#include <hip/hip_runtime.h>
#include <hip/hip_bf16.h>

#define NUM_GT 25
#define NUM_PRED 40
#define PAD 32         // 128 B between global words

// ws u32 word offsets (each on its own 128B line):
//   GT_W(b), b=0..24 : g_gt(b) = sum |gt - b|     (SAD accumulators)
//   PR_W(p), p=0..39 : g_pr(p) = sum |pred - p|
//   OV_W(p), p=0..40 : overlap bitmask row p
#define GT_W(b)  ((b) * PAD)
#define PR_W(p)  ((25 + (p)) * PAD)
#define OV_W(p)  ((65 + (p)) * PAD)
#define WS_WORDS (106 * PAD)

#define GRID 1024
#define BLOCK 256

// SAD: prefer the builtin (gives the scheduler full freedom); asm fallback.
#if defined(__has_builtin)
#  if __has_builtin(__builtin_amdgcn_sad_u8)
#    define SAD(A, W, K) (A) = __builtin_amdgcn_sad_u8((W), (K), (A))
#  endif
#endif
#ifndef SAD
#  define SAD(A, W, K) asm("v_sad_u8 %0, %1, %2, %0" : "+v"(A) : "v"(W), "s"(K))
#endif

// per-quad: unconditional no-return LDS ds_or (fire-and-forget; the wave
// never waits on these) + byte-pack. Replaces R6-R8's read-test-branch,
// the last per-iteration latency chain in the hot loop.
__device__ __forceinline__ void quad(
    int4 g, float4 p, unsigned* sovl, unsigned& G, unsigned& P)
{
    unsigned a0 = (unsigned)g.x, a1 = (unsigned)g.y;
    unsigned a2 = (unsigned)g.z, a3 = (unsigned)g.w;
    unsigned b0 = (unsigned)p.x, b1 = (unsigned)p.y;
    unsigned b2 = (unsigned)p.z, b3 = (unsigned)p.w;
    atomicOr(&sovl[b0 & 63], 1u << (a0 & 31));
    atomicOr(&sovl[b1 & 63], 1u << (a1 & 31));
    atomicOr(&sovl[b2 & 63], 1u << (a2 & 31));
    atomicOr(&sovl[b3 & 63], 1u << (a3 & 31));
    G = a0 | (a1 << 8) | (a2 << 16) | (a3 << 24);
    P = b0 | (b1 << 8) | (b2 << 16) | (b3 << 24);
}

// ---------------------------------------------------------------------------
// SAD histogram: 16 voxels/lane/iter (8 x dwordx4 = 128 B/lane in flight),
// 65 SAD accumulators, no branches / no LDS reads in the hot loop.
// count(x==B) = (g(B-1) - 2g(B) + g(B+1)) / 2 recovered in the finisher.
// ---------------------------------------------------------------------------
__global__ __launch_bounds__(BLOCK, 3) void hist_kernel(
    const float* __restrict__ pred, const int* __restrict__ gt,
    unsigned* __restrict__ ws, int n)
{
    __shared__ unsigned sovl[64];
    __shared__ unsigned shist[66];
    __shared__ unsigned stash[4][16][34];

    const int tid  = threadIdx.x;
    const int lane = tid & 63;
    const int wave = tid >> 6;

    if (tid < 64) sovl[tid] = 0u;
    if (tid < 66) shist[tid] = 0u;
    __syncthreads();

    // acc[0..24] = g_gt(0..24); acc[25..64] = g_pr(0..39); acc[65] dummy
    unsigned acc[66];
    #pragma unroll
    for (int j = 0; j < 66; ++j) acc[j] = 0u;

    const int gtid   = blockIdx.x * BLOCK + tid;
    const int n16    = n >> 4;               // 16-voxel groups
    const int stride = GRID * BLOCK;
    const float4* __restrict__ p4 = (const float4*)pred;
    const int4* __restrict__  g4 = (const int4*)gt;

    for (int i = gtid; i < n16; i += stride) {
        const int q = i * 4;
        // ---- 8 loads issued together: 128 B/lane in flight ----
        int4  ga = g4[q],     gb = g4[q + 1], gc = g4[q + 2], gd = g4[q + 3];
        float4 pa = p4[q],    pb = p4[q + 1], pc = p4[q + 2], pd = p4[q + 3];

        unsigned GA, GB, GC, GD, PA, PB, PC, PD;
        quad(ga, pa, sovl, GA, PA);
        quad(gb, pb, sovl, GB, PB);
        quad(gc, pc, sovl, GC, PC);
        quad(gd, pd, sovl, GD, PD);

        #pragma unroll
        for (int b = 0; b < 25; ++b) {
            const unsigned K = (unsigned)(b * 0x01010101u);
            SAD(acc[b], GA, K); SAD(acc[b], GB, K);
            SAD(acc[b], GC, K); SAD(acc[b], GD, K);
        }
        #pragma unroll
        for (int b = 0; b < 40; ++b) {
            const unsigned K = (unsigned)(b * 0x01010101u);
            SAD(acc[25 + b], PA, K); SAD(acc[25 + b], PB, K);
            SAD(acc[25 + b], PC, K); SAD(acc[25 + b], PD, K);
        }
    }

    // scalar tail for n % 16 (none for 256^3; defensive, SAD semantics)
    if (blockIdx.x == 0 && tid == 0) {
        for (int v = n16 << 4; v < n; ++v) {
            int p = (int)pred[v];
            int g = gt[v];
            for (int b = 0; b < 25; ++b) atomicAdd(&ws[GT_W(b)], (unsigned)abs(g - b));
            for (int b = 0; b < 40; ++b) atomicAdd(&ws[PR_W(b)], (unsigned)abs(p - b));
            atomicOr(&ws[OV_W(min(max(p, 0), NUM_PRED))], 1u << (g & 31));
        }
    }

    // ---- epilogue: pair-packed u16 tree (per-lane acc <= 64 vox * 40 = 2560)
    #pragma unroll
    for (int jp = 0; jp < 33; ++jp) {
        unsigned v = acc[2 * jp] | (acc[2 * jp + 1] << 16);
        v += __shfl_down(v, 32, 64);          // halves <= 5120
        v += __shfl_down(v, 16, 64);          // halves <= 10240
        if (lane < 16) stash[wave][lane][jp] = v;
    }
    __syncthreads();

    for (int i = tid; i < 33 * 16; i += BLOCK) {
        int jp = i >> 4, sl = i & 15;
        unsigned a = stash[0][sl][jp] + stash[1][sl][jp]
                   + stash[2][sl][jp] + stash[3][sl][jp];   // halves <= 40960
        unsigned lo = a & 0xFFFFu, hi = a >> 16;
        lo += __shfl_down(lo, 8, 16);  hi += __shfl_down(hi, 8, 16);
        lo += __shfl_down(lo, 4, 16);  hi += __shfl_down(hi, 4, 16);
        lo += __shfl_down(lo, 2, 16);  hi += __shfl_down(hi, 2, 16);
        lo += __shfl_down(lo, 1, 16);  hi += __shfl_down(hi, 1, 16);
        if (sl == 0) {
            if (lo) atomicAdd(&shist[2 * jp], lo);
            if (hi && 2 * jp + 1 < 65) atomicAdd(&shist[2 * jp + 1], hi);
        }
    }
    __syncthreads();

    for (int i = tid; i < 65; i += BLOCK) {
        unsigned s = shist[i];
        if (s) atomicAdd(&ws[i * PAD], s);
    }
    if (tid < 41) {
        unsigned v = sovl[tid];
        if (v) atomicOr(&ws[OV_W(tid)], v);
    }
}

// ---------------------------------------------------------------------------
// Finisher: second-difference count extraction (exact int64) + fp64 dice
// (proven absmax = 0, rounds 6-11).
// ---------------------------------------------------------------------------
__global__ __launch_bounds__(64) void finish_kernel(
    const unsigned* __restrict__ ws, float* __restrict__ out, int n)
{
    __shared__ long long gg[25], gp[40], psz[41];
    __shared__ unsigned ov[41];
    const int lane = threadIdx.x;
    if (lane < 25) gg[lane] = (long long)ws[GT_W(lane)];
    if (lane < 40) gp[lane] = (long long)ws[PR_W(lane)];
    if (lane < 41) ov[lane] = ws[OV_W(lane)];
    __syncthreads();

    const long long N = n, Sg = gg[0], Sp = gp[0];

    if (lane < 41) {                         // pred_sizes[P], P = lane
        int P = lane;
        long long f;
        if (P == 0)       f = (N - gp[0] + gp[1]) / 2;
        else if (P <= 38) f = (gp[P - 1] - 2 * gp[P] + gp[P + 1]) / 2;
        else if (P == 39) f = (gp[38] - 2 * gp[39] + (40 * N - Sp)) / 2;
        else              f = (gp[39] - 39 * N + Sp) / 2;   // P = 40
        psz[P] = f;
    }
    __syncthreads();

    double dice = 0.0;
    int present = 0;
    if (lane < 25) {                         // gt component label L = lane+1
        int L = lane + 1;
        long long gs;
        if (L <= 23)      gs = (gg[L - 1] - 2 * gg[L] + gg[L + 1]) / 2;
        else if (L == 24) gs = (gg[23] - 2 * gg[24] + (25 * N - Sg)) / 2;
        else              gs = (gg[24] - 24 * N + Sg) / 2;  // L = 25
        if (gs > 0) {
            present = 1;
            double un = 0.0;
            const unsigned bit = 1u << L;
            for (int p = 0; p < 41; ++p)
                if (ov[p] & bit) un += (double)psz[p];
            dice = 2.0 * (double)gs / (un + (double)gs + 1.0);
        }
    }
    int fp = 0;
    if (lane < 41) {
        if (psz[lane] > 0 && (ov[lane] & 0x3FFFFFEu) == 0) fp = 1;
    }

    int num_gt = __popcll(__ballot(present != 0));
    int nfp    = __popcll(__ballot(fp != 0));
    #pragma unroll
    for (int o = 32; o >= 1; o >>= 1) dice += __shfl_xor(dice, o, 64);

    if (lane == 0) out[0] = (float)(dice / (double)(num_gt + nfp));
}

extern "C" void kernel_launch(void* const* d_in, const int* in_sizes, int n_in,
                              void* d_out, int out_size, void* d_ws, size_t ws_size,
                              hipStream_t stream) {
    const float* pred = (const float*)d_in[0];
    const int* gt = (const int*)d_in[1];
    float* out = (float*)d_out;
    unsigned* ws = (unsigned*)d_ws;
    const int n = in_sizes[0];

    hipMemsetAsync(ws, 0, WS_WORDS * sizeof(unsigned), stream);

    hist_kernel<<<GRID, BLOCK, 0, stream>>>(pred, gt, ws, n);
    finish_kernel<<<1, 64, 0, stream>>>(ws, out, n);
}